// Round 10
// baseline (661.935 us; speedup 1.0000x reference)
//
#include <hip/hip_runtime.h>
#include <hip/hip_bf16.h>
#include <math.h>

// Dims (compile-time constants for this problem)
#define Bb 2
#define Tt 1024
#define Dd 512
#define Hh 8
#define Kk 64
#define Vv 64
#define BT (Bb*Tt)          // 2048
#define HK (Hh*Kk)          // 512

// hyperparams
#define B1c 0.9f
#define B2c 0.999f
#define LRc 1e-3f
#define SCALEc 0.125f       // 64^-0.5

// ---------------------------------------------------------------------------
// fp32 tiled GEMM: C[M,N] = A[M,K] @ W[K,N], M=2048, N=512, K=512
// ---------------------------------------------------------------------------
__device__ __forceinline__ void gemm_body(const float* __restrict__ A,
                                          const float* __restrict__ Bm,
                                          float* __restrict__ C) {
  constexpr int N = 512, Kd = 512;
  __shared__ float As[16][68];   // [k][m], padded
  __shared__ float Bs[16][68];   // [k][n]
  const int tid = threadIdx.x;
  const int bm = blockIdx.x * 64;
  const int bn = blockIdx.y * 64;
  const int tr = (tid >> 4) << 2;       // 0..60
  const int tc = (tid & 15) << 2;       // 0..60
  const int ar = tid >> 2;              // A tile row 0..63
  const int ak = (tid & 3) << 2;        // A tile k-col {0,4,8,12}
  const int bk = tid >> 4;              // B tile k-row 0..15
  const int bn4 = (tid & 15) << 2;      // B tile n-col
  float acc[4][4] = {};
  for (int k0 = 0; k0 < Kd; k0 += 16) {
    float4 av = *(const float4*)(A + (size_t)(bm + ar) * Kd + k0 + ak);
    float4 bv = *(const float4*)(Bm + (size_t)(k0 + bk) * N + bn + bn4);
    __syncthreads();
    As[ak + 0][ar] = av.x;
    As[ak + 1][ar] = av.y;
    As[ak + 2][ar] = av.z;
    As[ak + 3][ar] = av.w;
    *(float4*)&Bs[bk][bn4] = bv;
    __syncthreads();
#pragma unroll
    for (int kk = 0; kk < 16; ++kk) {
      float4 a = *(const float4*)&As[kk][tr];
      float4 b = *(const float4*)&Bs[kk][tc];
      const float ai[4] = {a.x, a.y, a.z, a.w};
      const float bj[4] = {b.x, b.y, b.z, b.w};
#pragma unroll
      for (int i = 0; i < 4; ++i)
#pragma unroll
        for (int j = 0; j < 4; ++j) acc[i][j] += ai[i] * bj[j];
    }
  }
#pragma unroll
  for (int i = 0; i < 4; ++i) {
    float4 o4 = {acc[i][0], acc[i][1], acc[i][2], acc[i][3]};
    *(float4*)(C + (size_t)(bm + tr + i) * N + bn + tc) = o4;
  }
}

__global__ __launch_bounds__(256) void gemm3_kernel(
    const float* __restrict__ x,
    const float* __restrict__ Wq, const float* __restrict__ Wk,
    const float* __restrict__ Wv,
    float* __restrict__ qp, float* __restrict__ kp, float* __restrict__ vp) {
  const float* W; float* Cp;
  if (blockIdx.z == 0)      { W = Wq; Cp = qp; }
  else if (blockIdx.z == 1) { W = Wk; Cp = kp; }
  else                      { W = Wv; Cp = vp; }
  gemm_body(x, W, Cp);
}

__global__ __launch_bounds__(256) void gemm1_kernel(
    const float* __restrict__ A, const float* __restrict__ W,
    float* __restrict__ C) {
  gemm_body(A, W, C);
}

// ---------------------------------------------------------------------------
// beta = sigmoid(x @ Wb), Wb:[512,8] -> beta:[B*T,8]
// ---------------------------------------------------------------------------
__global__ __launch_bounds__(256) void beta_kernel(const float* __restrict__ x,
                                                   const float* __restrict__ Wb,
                                                   float* __restrict__ beta) {
  int gid = blockIdx.x * blockDim.x + threadIdx.x;  // 0 .. 16383
  int bt = gid >> 3, h = gid & 7;
  const float* xr = x + (size_t)bt * Dd;
  float s = 0.f;
  for (int d = 0; d < Dd; ++d) s += xr[d] * Wb[d * Hh + h];
  beta[gid] = 1.f / (1.f + expf(-s));
}

// ---------------------------------------------------------------------------
// causal depthwise conv(4) + SiLU (+ optional L2 norm over K, + scale for q)
// ---------------------------------------------------------------------------
__global__ __launch_bounds__(256) void conv_kernel(
    const float* __restrict__ qp, const float* __restrict__ kp,
    const float* __restrict__ vp,
    const float* __restrict__ cwq, const float* __restrict__ cwk,
    const float* __restrict__ cwv,
    float* __restrict__ qc, float* __restrict__ kc, float* __restrict__ vc) {
  const int mode = blockIdx.z;
  const float* pre; const float* cw; float* post;
  if (mode == 0)      { pre = qp; cw = cwq; post = qc; }
  else if (mode == 1) { pre = kp; cw = cwk; post = kc; }
  else                { pre = vp; cw = cwv; post = vc; }

  const int idx = blockIdx.x * 4 + (threadIdx.x >> 6);   // (b,t,h) id, 0..16383
  const int lane = threadIdx.x & 63;
  const int b = idx >> 13;           // /(T*H)
  const int th = idx & 8191;
  const int t = th >> 3;
  const int h = th & 7;
  const int ch = h * 64 + lane;

  float y = 0.f;
#pragma unroll
  for (int i = 0; i < 4; ++i) {
    int tt = t + i - 3;
    if (tt >= 0)
      y += pre[((size_t)(b * Tt + tt)) * HK + ch] * cw[ch * 4 + i];
  }
  // SiLU
  y = y / (1.f + expf(-y));
  if (mode < 2) {
    float ss = y * y;
#pragma unroll
    for (int off = 32; off; off >>= 1) ss += __shfl_xor(ss, off, 64);
    y *= rsqrtf(ss + 1e-6f);
    if (mode == 0) y *= SCALEc;
  }
  post[((size_t)(b * Tt + t)) * HK + ch] = y;
}

// ---------------------------------------------------------------------------
// Butterfly partial sums, all-VALU-pipe.
// reduce32: sums within each 32-lane half (DPP xor1/2 + mirrors + permlane16).
// ---------------------------------------------------------------------------
template <int CTRL>
__device__ __forceinline__ float dpp_add(float v) {
  int y = __builtin_amdgcn_update_dpp(0, __float_as_int(v), CTRL, 0xF, 0xF, true);
  return v + __int_as_float(y);
}

typedef unsigned uint2_t __attribute__((ext_vector_type(2)));

__device__ __forceinline__ float xor16_add(float x) {
#if __has_builtin(__builtin_amdgcn_permlane16_swap)
  uint2_t r = __builtin_amdgcn_permlane16_swap(__float_as_uint(x), __float_as_uint(x),
                                               false, false);
  return __uint_as_float(r.x) + __uint_as_float(r.y);
#else
  int y = __builtin_amdgcn_ds_swizzle(__float_as_int(x), 0x401F);  // xor 16
  return x + __int_as_float(y);
#endif
}

template <bool NOX>
__device__ __forceinline__ float reduce32x(float x) {
  if constexpr (!NOX) {
    x = dpp_add<0xB1>(x);   // quad_perm xor 1
    x = dpp_add<0x4E>(x);   // quad_perm xor 2
    x = dpp_add<0x141>(x);  // row_half_mirror (xor 4)
    x = dpp_add<0x140>(x);  // row_mirror (xor 8)
    x = xor16_add(x);       // xor 16 -> each 32-half holds its own total
  }
  return x;
}

// ---------------------------------------------------------------------------
// sequential IVON delta-rule scan — LDS-staged (R9 structure), scaled state.
//
// Scaled state (exact algebra): G=10g, H=1000h:
//   G' = B1*G + gr          (weight folded out)
//   H' = B2*H + gr^2
//   S' = S - lrb*G*rcp(0.001*H + 1),  lrb = 0.1*LRc*beta
//
// template<REPS, NOX>: NOX compiles out the cross-lane reduce stages
// (ablation measuring their true cost: issue + dependent latency + hazards).
// REPS=4 for the ablation so its dispatches dominate the profile top-5.
// ---------------------------------------------------------------------------
#define TC 16   // steps per LDS tile

template <int REPS, bool NOX>
__device__ __forceinline__ void scan_body(
    const float* __restrict__ qc, const float* __restrict__ kc,
    const float* __restrict__ vc, const float* __restrict__ beta,
    float* __restrict__ o) {
  __shared__ float4 kq[2][TC][64];   // {k0,k1,q0,q1} per k-pair
  __shared__ float2 vb[2][TC][8];    // {v[col], lrb} per column

  const int tid  = threadIdx.x;
  const int lane = tid & 63;
  const int w    = tid >> 6;          // wave 0..3
  const int kg   = lane & 31;         // k-group: holds k = 2kg, 2kg+1
  const int c    = lane >> 5;         // column within pair
  const int bid  = blockIdx.x;        // 0..127
  const int vq8  = bid >> 4;          // 0..7  (column octet)
  const int bh   = bid & 15;          // bid%8 == bh%8 -> XCD affinity
  const int b = bh >> 3, h = bh & 7;
  const int colbase = vq8 * 8;
  const int cc = w * 2 + c;           // column within block 0..7
  const int v  = colbase + cc;        // global v column 0..63

  const size_t base2 = ((size_t)b * Tt) * HK + h * 64;
  const float* bp = beta + ((size_t)b * Tt) * Hh + h;
  float* op = o + base2 + v;

  // staging thread mapping
  const int sr = tid >> 4;            // k/q row 0..15
  const int sm = tid & 15;            // float4 col group
  const int vr = tid >> 3;            // v row 0..15 (tid<128)
  const int v8 = tid & 7;             // v col 0..7

  float S0 = 0, S1 = 0, H0 = 0, H1 = 0, G0 = 0, G1 = 0;

  for (int rep = 0; rep < REPS; ++rep) {
    // ---- prologue: stage tile 0 into buffer 0 ----
    {
      float4 k4 = *(const float4*)(kc + base2 + (size_t)sr * HK + sm * 4);
      float4 q4 = *(const float4*)(qc + base2 + (size_t)sr * HK + sm * 4);
      kq[0][sr][sm * 2 + 0] = make_float4(k4.x, k4.y, q4.x, q4.y);
      kq[0][sr][sm * 2 + 1] = make_float4(k4.z, k4.w, q4.z, q4.w);
      if (tid < 128) {
        float vv = vc[base2 + (size_t)vr * HK + colbase + v8];
        float lb = (0.1f * LRc) * bp[(size_t)vr * Hh];
        vb[0][vr][v8] = make_float2(vv, lb);
      }
      __syncthreads();
    }

    for (int tile = 0; tile < Tt / TC; ++tile) {
      const int d = tile & 1;
      const int t0 = tile * TC;
      const int more = (tile + 1 < Tt / TC);
      const int tn = more ? t0 + TC : t0;   // clamped

      // issue next tile's global loads NOW (completion hidden under compute)
      float4 nk = *(const float4*)(kc + base2 + (size_t)(tn + sr) * HK + sm * 4);
      float4 nq = *(const float4*)(qc + base2 + (size_t)(tn + sr) * HK + sm * 4);
      float  nv = 0.f, nb = 0.f;
      if (tid < 128) {
        nv = vc[base2 + (size_t)(tn + vr) * HK + colbase + v8];
        nb = (0.1f * LRc) * bp[(size_t)(tn + vr) * Hh];
      }

      // 16 steps from buffer d; LDS->reg prefetch one step ahead
      float4 kqc = kq[d][0][kg];
      float2 vbc = vb[d][0][cc];
#pragma unroll
      for (int s = 0; s < TC; ++s) {
        float4 kqn; float2 vbn;
        if (s + 1 < TC) {
          kqn = kq[d][s + 1][kg];
          vbn = vb[d][s + 1][cc];
        }
        const float kvx = kqc.x, kvy = kqc.y, qvx = kqc.z, qvy = kqc.w;
        const float vv = vbc.x, lrb = vbc.y;

        const float pred = reduce32x<NOX>(fmaf(kvx, S0, kvy * S1));
        const float diff = pred - vv;
        const float gr0 = kvx * diff;
        const float gr1 = kvy * diff;
        G0 = fmaf(B1c, G0, gr0);
        G1 = fmaf(B1c, G1, gr1);
        H0 = fmaf(B2c, H0, gr0 * gr0);
        H1 = fmaf(B2c, H1, gr1 * gr1);
        const float d0 = fmaf(H0, 0.001f, 1.0f);
        const float d1 = fmaf(H1, 0.001f, 1.0f);
        S0 = fmaf(-lrb, G0 * __builtin_amdgcn_rcpf(d0), S0);
        S1 = fmaf(-lrb, G1 * __builtin_amdgcn_rcpf(d1), S1);
        const float ro = reduce32x<NOX>(fmaf(qvx, S0, qvy * S1));
        if (kg == 0) op[(size_t)(t0 + s) * HK] = ro;  // lanes 0,32
        if (s + 1 < TC) { kqc = kqn; vbc = vbn; }
      }

      // write next tile into the other buffer; single barrier per tile
      if (more) {
        kq[d ^ 1][sr][sm * 2 + 0] = make_float4(nk.x, nk.y, nq.x, nq.y);
        kq[d ^ 1][sr][sm * 2 + 1] = make_float4(nk.z, nk.w, nq.z, nq.w);
        if (tid < 128) vb[d ^ 1][vr][v8] = make_float2(nv, nb);
      }
      __syncthreads();
    }
  }
}

__global__ __launch_bounds__(256) void scan_kernel(
    const float* __restrict__ qc, const float* __restrict__ kc,
    const float* __restrict__ vc, const float* __restrict__ beta,
    float* __restrict__ o) {
  scan_body<1, false>(qc, kc, vc, beta, o);
}

// Ablation: identical body, cross-lane reduces compiled out, 4x steps,
// writes to a dead workspace buffer. Its dispatch duration (top-5 table)
// isolates the true cost of the cross-lane stages.
__global__ __launch_bounds__(256) void scan_abl_nox(
    const float* __restrict__ qc, const float* __restrict__ kc,
    const float* __restrict__ vc, const float* __restrict__ beta,
    float* __restrict__ o) {
  scan_body<4, true>(qc, kc, vc, beta, o);
}

// ---------------------------------------------------------------------------
// RMSNorm over V=64 (in-place), * rms_w
// ---------------------------------------------------------------------------
__global__ __launch_bounds__(256) void rmsnorm_kernel(float* __restrict__ o,
                                                      const float* __restrict__ rmsw) {
  const int idx = blockIdx.x * 4 + (threadIdx.x >> 6);  // (b,t,h), 0..16383
  const int lane = threadIdx.x & 63;
  float* p = o + (size_t)idx * 64;
  float y = p[lane];
  float ss = y * y;
#pragma unroll
  for (int off = 32; off; off >>= 1) ss += __shfl_xor(ss, off, 64);
  y = y * rsqrtf(ss * (1.f / 64.f) + 1e-5f) * rmsw[lane];
  p[lane] = y;
}

// ---------------------------------------------------------------------------
extern "C" void kernel_launch(void* const* d_in, const int* in_sizes, int n_in,
                              void* d_out, int out_size, void* d_ws, size_t ws_size,
                              hipStream_t stream) {
  const float* x    = (const float*)d_in[0];
  const float* Wq   = (const float*)d_in[1];
  const float* Wk   = (const float*)d_in[2];
  const float* Wv   = (const float*)d_in[3];
  const float* Wb   = (const float*)d_in[4];
  const float* cwq  = (const float*)d_in[5];
  const float* cwk  = (const float*)d_in[6];
  const float* cwv  = (const float*)d_in[7];
  const float* rmsw = (const float*)d_in[8];
  const float* Wo   = (const float*)d_in[9];
  float* out = (float*)d_out;
  float* ws  = (float*)d_ws;

  const size_t SZ = (size_t)BT * HK;   // 1,048,576 floats
  float* qp   = ws;            // pre-conv q   (later reused as scan output)
  float* kp   = ws + 1 * SZ;   // pre-conv k   (dead after conv -> abl scratch)
  float* vp   = ws + 2 * SZ;
  float* qc   = ws + 3 * SZ;
  float* kc   = ws + 4 * SZ;
  float* vc   = ws + 5 * SZ;
  float* beta = ws + 6 * SZ;   // 16384 floats
  float* on   = qp;            // scan output / rmsnorm in-place (qp dead then)

  // 1. projections q,k,v
  gemm3_kernel<<<dim3(BT / 64, HK / 64, 3), 256, 0, stream>>>(x, Wq, Wk, Wv, qp, kp, vp);
  // 2. beta
  beta_kernel<<<dim3(BT * Hh / 256), 256, 0, stream>>>(x, Wb, beta);
  // 3. conv + silu + l2norm
  conv_kernel<<<dim3(Bb * Tt * Hh / 4, 1, 3), 256, 0, stream>>>(
      qp, kp, vp, cwq, cwk, cwv, qc, kc, vc);
  // 4. sequential scan: 128 blocks x 4 waves; packed LDS operands
  scan_kernel<<<dim3(Bb * Hh * (Vv / 8)), 256, 0, stream>>>(
      qc, kc, vc, beta, on);
  // 5. RMSNorm (in-place)
  rmsnorm_kernel<<<dim3(Bb * Tt * Hh / 4), 256, 0, stream>>>(on, rmsw);
  // 6. output projection
  gemm1_kernel<<<dim3(BT / 64, HK / 64, 1), 256, 0, stream>>>(on, Wo, out);
  // 7. ABLATION (measurement only): same scan minus cross-lane stages, 4x
  //    steps, output to dead kp buffer. Runs last; corrupts nothing.
  scan_abl_nox<<<dim3(Bb * Hh * (Vv / 8)), 256, 0, stream>>>(
      qc, kc, vc, beta, kp);
}

// Round 11
// 308.211 us; speedup vs baseline: 2.1477x; 2.1477x over previous
//
#include <hip/hip_runtime.h>
#include <hip/hip_bf16.h>
#include <math.h>

// Dims (compile-time constants for this problem)
#define Bb 2
#define Tt 1024
#define Dd 512
#define Hh 8
#define Kk 64
#define Vv 64
#define BT (Bb*Tt)          // 2048
#define HK (Hh*Kk)          // 512

// hyperparams
#define B1c 0.9f
#define B2c 0.999f
#define LRc 1e-3f
#define SCALEc 0.125f       // 64^-0.5

// ---------------------------------------------------------------------------
// fp32 tiled GEMM: C[M,N] = A[M,K] @ W[K,N], M=2048, N=512, K=512
// ---------------------------------------------------------------------------
__device__ __forceinline__ void gemm_body(const float* __restrict__ A,
                                          const float* __restrict__ Bm,
                                          float* __restrict__ C) {
  constexpr int N = 512, Kd = 512;
  __shared__ float As[16][68];   // [k][m], padded
  __shared__ float Bs[16][68];   // [k][n]
  const int tid = threadIdx.x;
  const int bm = blockIdx.x * 64;
  const int bn = blockIdx.y * 64;
  const int tr = (tid >> 4) << 2;       // 0..60
  const int tc = (tid & 15) << 2;       // 0..60
  const int ar = tid >> 2;              // A tile row 0..63
  const int ak = (tid & 3) << 2;        // A tile k-col {0,4,8,12}
  const int bk = tid >> 4;              // B tile k-row 0..15
  const int bn4 = (tid & 15) << 2;      // B tile n-col
  float acc[4][4] = {};
  for (int k0 = 0; k0 < Kd; k0 += 16) {
    float4 av = *(const float4*)(A + (size_t)(bm + ar) * Kd + k0 + ak);
    float4 bv = *(const float4*)(Bm + (size_t)(k0 + bk) * N + bn + bn4);
    __syncthreads();
    As[ak + 0][ar] = av.x;
    As[ak + 1][ar] = av.y;
    As[ak + 2][ar] = av.z;
    As[ak + 3][ar] = av.w;
    *(float4*)&Bs[bk][bn4] = bv;
    __syncthreads();
#pragma unroll
    for (int kk = 0; kk < 16; ++kk) {
      float4 a = *(const float4*)&As[kk][tr];
      float4 b = *(const float4*)&Bs[kk][tc];
      const float ai[4] = {a.x, a.y, a.z, a.w};
      const float bj[4] = {b.x, b.y, b.z, b.w};
#pragma unroll
      for (int i = 0; i < 4; ++i)
#pragma unroll
        for (int j = 0; j < 4; ++j) acc[i][j] += ai[i] * bj[j];
    }
  }
#pragma unroll
  for (int i = 0; i < 4; ++i) {
    float4 o4 = {acc[i][0], acc[i][1], acc[i][2], acc[i][3]};
    *(float4*)(C + (size_t)(bm + tr + i) * N + bn + tc) = o4;
  }
}

__global__ __launch_bounds__(256) void gemm3_kernel(
    const float* __restrict__ x,
    const float* __restrict__ Wq, const float* __restrict__ Wk,
    const float* __restrict__ Wv,
    float* __restrict__ qp, float* __restrict__ kp, float* __restrict__ vp) {
  const float* W; float* Cp;
  if (blockIdx.z == 0)      { W = Wq; Cp = qp; }
  else if (blockIdx.z == 1) { W = Wk; Cp = kp; }
  else                      { W = Wv; Cp = vp; }
  gemm_body(x, W, Cp);
}

__global__ __launch_bounds__(256) void gemm1_kernel(
    const float* __restrict__ A, const float* __restrict__ W,
    float* __restrict__ C) {
  gemm_body(A, W, C);
}

// ---------------------------------------------------------------------------
// beta = sigmoid(x @ Wb), Wb:[512,8] -> beta:[B*T,8]
// ---------------------------------------------------------------------------
__global__ __launch_bounds__(256) void beta_kernel(const float* __restrict__ x,
                                                   const float* __restrict__ Wb,
                                                   float* __restrict__ beta) {
  int gid = blockIdx.x * blockDim.x + threadIdx.x;  // 0 .. 16383
  int bt = gid >> 3, h = gid & 7;
  const float* xr = x + (size_t)bt * Dd;
  float s = 0.f;
  for (int d = 0; d < Dd; ++d) s += xr[d] * Wb[d * Hh + h];
  beta[gid] = 1.f / (1.f + expf(-s));
}

// ---------------------------------------------------------------------------
// causal depthwise conv(4) + SiLU (+ optional L2 norm over K, + scale for q)
// ---------------------------------------------------------------------------
__global__ __launch_bounds__(256) void conv_kernel(
    const float* __restrict__ qp, const float* __restrict__ kp,
    const float* __restrict__ vp,
    const float* __restrict__ cwq, const float* __restrict__ cwk,
    const float* __restrict__ cwv,
    float* __restrict__ qc, float* __restrict__ kc, float* __restrict__ vc) {
  const int mode = blockIdx.z;
  const float* pre; const float* cw; float* post;
  if (mode == 0)      { pre = qp; cw = cwq; post = qc; }
  else if (mode == 1) { pre = kp; cw = cwk; post = kc; }
  else                { pre = vp; cw = cwv; post = vc; }

  const int idx = blockIdx.x * 4 + (threadIdx.x >> 6);   // (b,t,h) id, 0..16383
  const int lane = threadIdx.x & 63;
  const int b = idx >> 13;           // /(T*H)
  const int th = idx & 8191;
  const int t = th >> 3;
  const int h = th & 7;
  const int ch = h * 64 + lane;

  float y = 0.f;
#pragma unroll
  for (int i = 0; i < 4; ++i) {
    int tt = t + i - 3;
    if (tt >= 0)
      y += pre[((size_t)(b * Tt + tt)) * HK + ch] * cw[ch * 4 + i];
  }
  // SiLU
  y = y / (1.f + expf(-y));
  if (mode < 2) {
    float ss = y * y;
#pragma unroll
    for (int off = 32; off; off >>= 1) ss += __shfl_xor(ss, off, 64);
    y *= rsqrtf(ss + 1e-6f);
    if (mode == 0) y *= SCALEc;
  }
  post[((size_t)(b * Tt + t)) * HK + ch] = y;
}

// ---------------------------------------------------------------------------
// Butterfly partial sums, all-VALU-pipe.
// reduce32: sums within each 32-lane half (DPP xor1/2 + mirrors + permlane16).
// ---------------------------------------------------------------------------
template <int CTRL>
__device__ __forceinline__ float dpp_add(float v) {
  int y = __builtin_amdgcn_update_dpp(0, __float_as_int(v), CTRL, 0xF, 0xF, true);
  return v + __int_as_float(y);
}

typedef unsigned uint2_t __attribute__((ext_vector_type(2)));

__device__ __forceinline__ float xor16_add(float x) {
#if __has_builtin(__builtin_amdgcn_permlane16_swap)
  uint2_t r = __builtin_amdgcn_permlane16_swap(__float_as_uint(x), __float_as_uint(x),
                                               false, false);
  return __uint_as_float(r.x) + __uint_as_float(r.y);
#else
  int y = __builtin_amdgcn_ds_swizzle(__float_as_int(x), 0x401F);  // xor 16
  return x + __int_as_float(y);
#endif
}

__device__ __forceinline__ float reduce32(float x) {
  x = dpp_add<0xB1>(x);   // quad_perm xor 1
  x = dpp_add<0x4E>(x);   // quad_perm xor 2
  x = dpp_add<0x141>(x);  // row_half_mirror (xor 4)
  x = dpp_add<0x140>(x);  // row_mirror (xor 8)
  x = xor16_add(x);       // xor 16 -> each 32-half holds its own total
  return x;
}

// ---------------------------------------------------------------------------
// sequential IVON delta-rule scan — LDS-staged, 2 waves/SIMD for TLP.
//
// R10 ablation: cross-lane = 188cy/step, rest = 230cy (issue ~170 + misc).
// With 1 wave/SIMD every bubble is exposed. This round: 512-thread blocks
// (8 waves) -> HW places 2 waves per SIMD; their chain/cross-lane stalls
// overlap. Effective per-step ~ max(2*issue, W_solo)/2 ~ 210cy (~2x).
//
// One block = one (b,h) x 16 v-columns. Each wave packs 2 columns into its
// 32-lane halves (lane = c*32+kg, k = {2kg,2kg+1}); cc = w*2+c in 0..15.
// k/q staged shared (waves 0-3), v/lrb staged by waves 4-7.
// Scaled state (exact): G=10g, H=1000h, lrb=0.1*LRc*beta.
// ---------------------------------------------------------------------------
#define TC 16   // steps per LDS tile

__global__ __launch_bounds__(512) void scan_kernel(
    const float* __restrict__ qc, const float* __restrict__ kc,
    const float* __restrict__ vc, const float* __restrict__ beta,
    float* __restrict__ o) {
  __shared__ float4 kq[2][TC][64];   // {k0,k1,q0,q1} per k-pair
  __shared__ float2 vb[2][TC][16];   // {v[col], lrb} per column

  const int tid  = threadIdx.x;       // 0..511
  const int lane = tid & 63;
  const int w    = tid >> 6;          // wave 0..7
  const int kg   = lane & 31;         // k-group: holds k = 2kg, 2kg+1
  const int c    = lane >> 5;         // column within pair
  const int bid  = blockIdx.x;        // 0..63
  const int vq4  = bid >> 4;          // 0..3  (column 16-group)
  const int bh   = bid & 15;          // bid%8 == bh%8 -> XCD affinity
  const int b = bh >> 3, h = bh & 7;
  const int colbase = vq4 * 16;
  const int cc = w * 2 + c;           // column within block 0..15
  const int v  = colbase + cc;        // global v column 0..63

  const size_t base2 = ((size_t)b * Tt) * HK + h * 64;
  const float* bp = beta + ((size_t)b * Tt) * Hh + h;
  float* op = o + base2 + v;

  // staging thread mapping: threads 0-255 stage k/q; 256-511 stage v/beta
  const int sr = tid >> 4;            // k/q row 0..15   (tid<256)
  const int sm = tid & 15;            // float4 col group
  const int t2 = tid - 256;           // v/beta stager id (tid>=256)
  const int vr = t2 >> 4;             // v row 0..15
  const int vcc = t2 & 15;            // v col 0..15

  // ---- prologue: stage tile 0 into buffer 0 ----
  {
    if (tid < 256) {
      float4 k4 = *(const float4*)(kc + base2 + (size_t)sr * HK + sm * 4);
      float4 q4 = *(const float4*)(qc + base2 + (size_t)sr * HK + sm * 4);
      kq[0][sr][sm * 2 + 0] = make_float4(k4.x, k4.y, q4.x, q4.y);
      kq[0][sr][sm * 2 + 1] = make_float4(k4.z, k4.w, q4.z, q4.w);
    } else {
      float vv = vc[base2 + (size_t)vr * HK + colbase + vcc];
      float lb = (0.1f * LRc) * bp[(size_t)vr * Hh];
      vb[0][vr][vcc] = make_float2(vv, lb);
    }
    __syncthreads();
  }

  float S0 = 0, S1 = 0, H0 = 0, H1 = 0, G0 = 0, G1 = 0;

  for (int tile = 0; tile < Tt / TC; ++tile) {
    const int d = tile & 1;
    const int t0 = tile * TC;
    const int more = (tile + 1 < Tt / TC);
    const int tn = more ? t0 + TC : t0;   // clamped (rewrite, unused)

    // issue next tile's global loads NOW (completion hidden under compute)
    float4 nk, nq; float nv = 0.f, nb = 0.f;
    if (tid < 256) {
      nk = *(const float4*)(kc + base2 + (size_t)(tn + sr) * HK + sm * 4);
      nq = *(const float4*)(qc + base2 + (size_t)(tn + sr) * HK + sm * 4);
    } else {
      nv = vc[base2 + (size_t)(tn + vr) * HK + colbase + vcc];
      nb = (0.1f * LRc) * bp[(size_t)(tn + vr) * Hh];
    }

    // 16 steps from buffer d; LDS->reg prefetch one step ahead
    float4 kqc = kq[d][0][kg];
    float2 vbc = vb[d][0][cc];
#pragma unroll
    for (int s = 0; s < TC; ++s) {
      float4 kqn; float2 vbn;
      if (s + 1 < TC) {
        kqn = kq[d][s + 1][kg];
        vbn = vb[d][s + 1][cc];
      }
      const float kvx = kqc.x, kvy = kqc.y, qvx = kqc.z, qvy = kqc.w;
      const float vv = vbc.x, lrb = vbc.y;

      const float pred = reduce32(fmaf(kvx, S0, kvy * S1));
      const float diff = pred - vv;
      const float gr0 = kvx * diff;
      const float gr1 = kvy * diff;
      G0 = fmaf(B1c, G0, gr0);
      G1 = fmaf(B1c, G1, gr1);
      H0 = fmaf(B2c, H0, gr0 * gr0);
      H1 = fmaf(B2c, H1, gr1 * gr1);
      const float d0 = fmaf(H0, 0.001f, 1.0f);
      const float d1 = fmaf(H1, 0.001f, 1.0f);
      S0 = fmaf(-lrb, G0 * __builtin_amdgcn_rcpf(d0), S0);
      S1 = fmaf(-lrb, G1 * __builtin_amdgcn_rcpf(d1), S1);
      const float ro = reduce32(fmaf(qvx, S0, qvy * S1));
      if (kg == 0) op[(size_t)(t0 + s) * HK] = ro;  // lanes 0,32: one per col
      if (s + 1 < TC) { kqc = kqn; vbc = vbn; }
    }

    // write next tile into the other buffer; single barrier per tile
    if (more) {
      if (tid < 256) {
        kq[d ^ 1][sr][sm * 2 + 0] = make_float4(nk.x, nk.y, nq.x, nq.y);
        kq[d ^ 1][sr][sm * 2 + 1] = make_float4(nk.z, nk.w, nq.z, nq.w);
      } else {
        vb[d ^ 1][vr][vcc] = make_float2(nv, nb);
      }
    }
    __syncthreads();
  }
}

// ---------------------------------------------------------------------------
// RMSNorm over V=64 (in-place), * rms_w
// ---------------------------------------------------------------------------
__global__ __launch_bounds__(256) void rmsnorm_kernel(float* __restrict__ o,
                                                      const float* __restrict__ rmsw) {
  const int idx = blockIdx.x * 4 + (threadIdx.x >> 6);  // (b,t,h), 0..16383
  const int lane = threadIdx.x & 63;
  float* p = o + (size_t)idx * 64;
  float y = p[lane];
  float ss = y * y;
#pragma unroll
  for (int off = 32; off; off >>= 1) ss += __shfl_xor(ss, off, 64);
  y = y * rsqrtf(ss * (1.f / 64.f) + 1e-5f) * rmsw[lane];
  p[lane] = y;
}

// ---------------------------------------------------------------------------
extern "C" void kernel_launch(void* const* d_in, const int* in_sizes, int n_in,
                              void* d_out, int out_size, void* d_ws, size_t ws_size,
                              hipStream_t stream) {
  const float* x    = (const float*)d_in[0];
  const float* Wq   = (const float*)d_in[1];
  const float* Wk   = (const float*)d_in[2];
  const float* Wv   = (const float*)d_in[3];
  const float* Wb   = (const float*)d_in[4];
  const float* cwq  = (const float*)d_in[5];
  const float* cwk  = (const float*)d_in[6];
  const float* cwv  = (const float*)d_in[7];
  const float* rmsw = (const float*)d_in[8];
  const float* Wo   = (const float*)d_in[9];
  float* out = (float*)d_out;
  float* ws  = (float*)d_ws;

  const size_t SZ = (size_t)BT * HK;   // 1,048,576 floats
  float* qp   = ws;            // pre-conv q   (later reused as scan output)
  float* kp   = ws + 1 * SZ;
  float* vp   = ws + 2 * SZ;
  float* qc   = ws + 3 * SZ;
  float* kc   = ws + 4 * SZ;
  float* vc   = ws + 5 * SZ;
  float* beta = ws + 6 * SZ;   // 16384 floats
  float* on   = qp;            // scan output / rmsnorm in-place (qp dead then)

  // 1. projections q,k,v
  gemm3_kernel<<<dim3(BT / 64, HK / 64, 3), 256, 0, stream>>>(x, Wq, Wk, Wv, qp, kp, vp);
  // 2. beta
  beta_kernel<<<dim3(BT * Hh / 256), 256, 0, stream>>>(x, Wb, beta);
  // 3. conv + silu + l2norm
  conv_kernel<<<dim3(Bb * Tt * Hh / 4, 1, 3), 256, 0, stream>>>(
      qp, kp, vp, cwq, cwk, cwv, qc, kc, vc);
  // 4. sequential scan: 64 blocks x 8 waves (2 waves/SIMD), 16 cols/block
  scan_kernel<<<dim3(Bb * Hh * (Vv / 16)), 512, 0, stream>>>(
      qc, kc, vc, beta, on);
  // 5. RMSNorm (in-place)
  rmsnorm_kernel<<<dim3(Bb * Tt * Hh / 4), 256, 0, stream>>>(on, rmsw);
  // 6. output projection
  gemm1_kernel<<<dim3(BT / 64, HK / 64, 1), 256, 0, stream>>>(on, Wo, out);
}

// Round 12
// 282.123 us; speedup vs baseline: 2.3463x; 1.0925x over previous
//
#include <hip/hip_runtime.h>
#include <hip/hip_bf16.h>
#include <math.h>

// Dims (compile-time constants for this problem)
#define Bb 2
#define Tt 1024
#define Dd 512
#define Hh 8
#define Kk 64
#define Vv 64
#define BT (Bb*Tt)          // 2048
#define HK (Hh*Kk)          // 512

// hyperparams
#define B1c 0.9f
#define B2c 0.999f
#define LRc 1e-3f
#define SCALEc 0.125f       // 64^-0.5

// ---------------------------------------------------------------------------
// fp32 tiled GEMM: C[M,N] = A[M,K] @ W[K,N], M=2048, N=512, K=512
// ---------------------------------------------------------------------------
__device__ __forceinline__ void gemm_body(const float* __restrict__ A,
                                          const float* __restrict__ Bm,
                                          float* __restrict__ C) {
  constexpr int N = 512, Kd = 512;
  __shared__ float As[16][68];   // [k][m], padded
  __shared__ float Bs[16][68];   // [k][n]
  const int tid = threadIdx.x;
  const int bm = blockIdx.x * 64;
  const int bn = blockIdx.y * 64;
  const int tr = (tid >> 4) << 2;       // 0..60
  const int tc = (tid & 15) << 2;       // 0..60
  const int ar = tid >> 2;              // A tile row 0..63
  const int ak = (tid & 3) << 2;        // A tile k-col {0,4,8,12}
  const int bk = tid >> 4;              // B tile k-row 0..15
  const int bn4 = (tid & 15) << 2;      // B tile n-col
  float acc[4][4] = {};
  for (int k0 = 0; k0 < Kd; k0 += 16) {
    float4 av = *(const float4*)(A + (size_t)(bm + ar) * Kd + k0 + ak);
    float4 bv = *(const float4*)(Bm + (size_t)(k0 + bk) * N + bn + bn4);
    __syncthreads();
    As[ak + 0][ar] = av.x;
    As[ak + 1][ar] = av.y;
    As[ak + 2][ar] = av.z;
    As[ak + 3][ar] = av.w;
    *(float4*)&Bs[bk][bn4] = bv;
    __syncthreads();
#pragma unroll
    for (int kk = 0; kk < 16; ++kk) {
      float4 a = *(const float4*)&As[kk][tr];
      float4 b = *(const float4*)&Bs[kk][tc];
      const float ai[4] = {a.x, a.y, a.z, a.w};
      const float bj[4] = {b.x, b.y, b.z, b.w};
#pragma unroll
      for (int i = 0; i < 4; ++i)
#pragma unroll
        for (int j = 0; j < 4; ++j) acc[i][j] += ai[i] * bj[j];
    }
  }
#pragma unroll
  for (int i = 0; i < 4; ++i) {
    float4 o4 = {acc[i][0], acc[i][1], acc[i][2], acc[i][3]};
    *(float4*)(C + (size_t)(bm + tr + i) * N + bn + tc) = o4;
  }
}

__global__ __launch_bounds__(256) void gemm3_kernel(
    const float* __restrict__ x,
    const float* __restrict__ Wq, const float* __restrict__ Wk,
    const float* __restrict__ Wv,
    float* __restrict__ qp, float* __restrict__ kp, float* __restrict__ vp) {
  const float* W; float* Cp;
  if (blockIdx.z == 0)      { W = Wq; Cp = qp; }
  else if (blockIdx.z == 1) { W = Wk; Cp = kp; }
  else                      { W = Wv; Cp = vp; }
  gemm_body(x, W, Cp);
}

__global__ __launch_bounds__(256) void gemm1_kernel(
    const float* __restrict__ A, const float* __restrict__ W,
    float* __restrict__ C) {
  gemm_body(A, W, C);
}

// ---------------------------------------------------------------------------
// beta = sigmoid(x @ Wb), Wb:[512,8] -> beta:[B*T,8]
// ---------------------------------------------------------------------------
__global__ __launch_bounds__(256) void beta_kernel(const float* __restrict__ x,
                                                   const float* __restrict__ Wb,
                                                   float* __restrict__ beta) {
  int gid = blockIdx.x * blockDim.x + threadIdx.x;  // 0 .. 16383
  int bt = gid >> 3, h = gid & 7;
  const float* xr = x + (size_t)bt * Dd;
  float s = 0.f;
  for (int d = 0; d < Dd; ++d) s += xr[d] * Wb[d * Hh + h];
  beta[gid] = 1.f / (1.f + expf(-s));
}

// ---------------------------------------------------------------------------
// causal depthwise conv(4) + SiLU (+ optional L2 norm over K, + scale for q)
// ---------------------------------------------------------------------------
__global__ __launch_bounds__(256) void conv_kernel(
    const float* __restrict__ qp, const float* __restrict__ kp,
    const float* __restrict__ vp,
    const float* __restrict__ cwq, const float* __restrict__ cwk,
    const float* __restrict__ cwv,
    float* __restrict__ qc, float* __restrict__ kc, float* __restrict__ vc) {
  const int mode = blockIdx.z;
  const float* pre; const float* cw; float* post;
  if (mode == 0)      { pre = qp; cw = cwq; post = qc; }
  else if (mode == 1) { pre = kp; cw = cwk; post = kc; }
  else                { pre = vp; cw = cwv; post = vc; }

  const int idx = blockIdx.x * 4 + (threadIdx.x >> 6);   // (b,t,h) id, 0..16383
  const int lane = threadIdx.x & 63;
  const int b = idx >> 13;           // /(T*H)
  const int th = idx & 8191;
  const int t = th >> 3;
  const int h = th & 7;
  const int ch = h * 64 + lane;

  float y = 0.f;
#pragma unroll
  for (int i = 0; i < 4; ++i) {
    int tt = t + i - 3;
    if (tt >= 0)
      y += pre[((size_t)(b * Tt + tt)) * HK + ch] * cw[ch * 4 + i];
  }
  // SiLU
  y = y / (1.f + expf(-y));
  if (mode < 2) {
    float ss = y * y;
#pragma unroll
    for (int off = 32; off; off >>= 1) ss += __shfl_xor(ss, off, 64);
    y *= rsqrtf(ss + 1e-6f);
    if (mode == 0) y *= SCALEc;
  }
  post[((size_t)(b * Tt + t)) * HK + ch] = y;
}

// ---------------------------------------------------------------------------
// All-DPP 16-lane butterfly sum (no permlane): quad_perm xor1, xor2,
// row_half_mirror (xor4-equivalent within 8), row_mirror (xor8 within 16).
// After the 4 stages every lane of each 16-group holds the group total.
// ---------------------------------------------------------------------------
template <int CTRL>
__device__ __forceinline__ float dpp_add(float v) {
  int y = __builtin_amdgcn_update_dpp(0, __float_as_int(v), CTRL, 0xF, 0xF, true);
  return v + __int_as_float(y);
}

__device__ __forceinline__ float reduce16(float x) {
  x = dpp_add<0xB1>(x);   // quad_perm(1,0,3,2)
  x = dpp_add<0x4E>(x);   // quad_perm(2,3,0,1)
  x = dpp_add<0x141>(x);  // row_half_mirror
  x = dpp_add<0x140>(x);  // row_mirror
  return x;
}

// ---------------------------------------------------------------------------
// sequential IVON delta-rule scan — W=16 lanes/col, L=4 k/lane, C=4 cols/wave.
//
// R11 lesson: wall = steps x per-step serial cost (issue + crosslane stalls);
// TLP cannot shorten it. This layout cuts BOTH terms vs the 32-lane pairing:
//  * reduce16 = 4 all-DPP stages (no permlane16_swap) -> 8 cheap stages/step.
//  * 4 columns share each reduce -> per-column issue ~halved (~57 VALU for
//    4 columns vs ~85 for 2).
// lane = cgrp*16 + g: column cc = w*4 + cgrp, k elements {4g..4g+3}.
// LDS staging (proven R9 infra): 16-step tiles, double-buffered,
// issue-early/write-late, 1-step-ahead LDS->reg prefetch.
// 64 blocks x 4 waves = 256 waves, 1/SIMD over 64 CUs.
// Scaled state (exact): G=10g, H=1000h, lrb=0.1*LRc*beta.
// ---------------------------------------------------------------------------
#define TC 16   // steps per LDS tile

__global__ __launch_bounds__(256) void scan_kernel(
    const float* __restrict__ qc, const float* __restrict__ kc,
    const float* __restrict__ vc, const float* __restrict__ beta,
    float* __restrict__ o) {
  __shared__ float4 ks[2][TC][16];   // k[4g..4g+3] per group
  __shared__ float4 qs[2][TC][16];
  __shared__ float2 vb[2][TC][16];   // {v[col], lrb} per column

  const int tid  = threadIdx.x;       // 0..255
  const int lane = tid & 63;
  const int w    = tid >> 6;          // wave 0..3
  const int g    = lane & 15;         // k-group: holds k = 4g..4g+3
  const int cgrp = lane >> 4;         // column group within wave 0..3
  const int bid  = blockIdx.x;        // 0..63
  const int vq   = bid >> 4;          // 0..3  (column 16-group)
  const int bh   = bid & 15;          // bid%8 == bh%8 -> XCD affinity
  const int b = bh >> 3, h = bh & 7;
  const int colbase = vq * 16;
  const int cc = w * 4 + cgrp;        // column within block 0..15
  const int v  = colbase + cc;        // global v column 0..63

  const size_t base2 = ((size_t)b * Tt) * HK + h * 64;
  const float* bp = beta + ((size_t)b * Tt) * Hh + h;
  float* op = o + base2 + v;

  // staging: each of 256 threads loads one k-float4, one q-float4, one v
  // scalar and the (broadcast) beta for its step row.
  const int sr = tid >> 4;            // step row 0..15
  const int sg = tid & 15;            // float4 group / v column

  // ---- prologue: stage tile 0 into buffer 0 ----
  {
    float4 k4 = *(const float4*)(kc + base2 + (size_t)sr * HK + sg * 4);
    float4 q4 = *(const float4*)(qc + base2 + (size_t)sr * HK + sg * 4);
    float  vv = vc[base2 + (size_t)sr * HK + colbase + sg];
    float  lb = (0.1f * LRc) * bp[(size_t)sr * Hh];
    ks[0][sr][sg] = k4;
    qs[0][sr][sg] = q4;
    vb[0][sr][sg] = make_float2(vv, lb);
    __syncthreads();
  }

  float S0 = 0, S1 = 0, S2 = 0, S3 = 0;
  float G0 = 0, G1 = 0, G2 = 0, G3 = 0;
  float H0 = 0, H1 = 0, H2 = 0, H3 = 0;

  for (int tile = 0; tile < Tt / TC; ++tile) {
    const int d = tile & 1;
    const int t0 = tile * TC;
    const int more = (tile + 1 < Tt / TC);
    const int tn = more ? t0 + TC : t0;   // clamped (rewrite, unused)

    // issue next tile's global loads NOW (completion hidden under compute)
    float4 nk = *(const float4*)(kc + base2 + (size_t)(tn + sr) * HK + sg * 4);
    float4 nq = *(const float4*)(qc + base2 + (size_t)(tn + sr) * HK + sg * 4);
    float  nv = vc[base2 + (size_t)(tn + sr) * HK + colbase + sg];
    float  nb = (0.1f * LRc) * bp[(size_t)(tn + sr) * Hh];

    // 16 steps from buffer d; LDS->reg prefetch one step ahead
    float4 kcur = ks[d][0][g];
    float4 qcur = qs[d][0][g];
    float2 vbc  = vb[d][0][cc];
#pragma unroll
    for (int s = 0; s < TC; ++s) {
      float4 knx, qnx; float2 vbn;
      if (s + 1 < TC) {
        knx = ks[d][s + 1][g];
        qnx = qs[d][s + 1][g];
        vbn = vb[d][s + 1][cc];
      }
      const float vv = vbc.x, lrb = vbc.y;

      const float pp = fmaf(kcur.x, S0, kcur.y * S1) +
                       fmaf(kcur.z, S2, kcur.w * S3);
      const float pred = reduce16(pp);
      const float diff = pred - vv;

      const float gr0 = kcur.x * diff;
      const float gr1 = kcur.y * diff;
      const float gr2 = kcur.z * diff;
      const float gr3 = kcur.w * diff;
      G0 = fmaf(B1c, G0, gr0);
      G1 = fmaf(B1c, G1, gr1);
      G2 = fmaf(B1c, G2, gr2);
      G3 = fmaf(B1c, G3, gr3);
      H0 = fmaf(B2c, H0, gr0 * gr0);
      H1 = fmaf(B2c, H1, gr1 * gr1);
      H2 = fmaf(B2c, H2, gr2 * gr2);
      H3 = fmaf(B2c, H3, gr3 * gr3);
      S0 = fmaf(-lrb, G0 * __builtin_amdgcn_rcpf(fmaf(H0, 0.001f, 1.0f)), S0);
      S1 = fmaf(-lrb, G1 * __builtin_amdgcn_rcpf(fmaf(H1, 0.001f, 1.0f)), S1);
      S2 = fmaf(-lrb, G2 * __builtin_amdgcn_rcpf(fmaf(H2, 0.001f, 1.0f)), S2);
      S3 = fmaf(-lrb, G3 * __builtin_amdgcn_rcpf(fmaf(H3, 0.001f, 1.0f)), S3);

      const float po = fmaf(qcur.x, S0, qcur.y * S1) +
                       fmaf(qcur.z, S2, qcur.w * S3);
      const float ro = reduce16(po);
      if (g == 0) op[(size_t)(t0 + s) * HK] = ro;  // 4 lanes/wave: 1 per col
      if (s + 1 < TC) { kcur = knx; qcur = qnx; vbc = vbn; }
    }

    // write next tile into the other buffer; single barrier per tile
    if (more) {
      ks[d ^ 1][sr][sg] = nk;
      qs[d ^ 1][sr][sg] = nq;
      vb[d ^ 1][sr][sg] = make_float2(nv, nb);
    }
    __syncthreads();
  }
}

// ---------------------------------------------------------------------------
// RMSNorm over V=64 (in-place), * rms_w
// ---------------------------------------------------------------------------
__global__ __launch_bounds__(256) void rmsnorm_kernel(float* __restrict__ o,
                                                      const float* __restrict__ rmsw) {
  const int idx = blockIdx.x * 4 + (threadIdx.x >> 6);  // (b,t,h), 0..16383
  const int lane = threadIdx.x & 63;
  float* p = o + (size_t)idx * 64;
  float y = p[lane];
  float ss = y * y;
#pragma unroll
  for (int off = 32; off; off >>= 1) ss += __shfl_xor(ss, off, 64);
  y = y * rsqrtf(ss * (1.f / 64.f) + 1e-5f) * rmsw[lane];
  p[lane] = y;
}

// ---------------------------------------------------------------------------
extern "C" void kernel_launch(void* const* d_in, const int* in_sizes, int n_in,
                              void* d_out, int out_size, void* d_ws, size_t ws_size,
                              hipStream_t stream) {
  const float* x    = (const float*)d_in[0];
  const float* Wq   = (const float*)d_in[1];
  const float* Wk   = (const float*)d_in[2];
  const float* Wv   = (const float*)d_in[3];
  const float* Wb   = (const float*)d_in[4];
  const float* cwq  = (const float*)d_in[5];
  const float* cwk  = (const float*)d_in[6];
  const float* cwv  = (const float*)d_in[7];
  const float* rmsw = (const float*)d_in[8];
  const float* Wo   = (const float*)d_in[9];
  float* out = (float*)d_out;
  float* ws  = (float*)d_ws;

  const size_t SZ = (size_t)BT * HK;   // 1,048,576 floats
  float* qp   = ws;            // pre-conv q   (later reused as scan output)
  float* kp   = ws + 1 * SZ;
  float* vp   = ws + 2 * SZ;
  float* qc   = ws + 3 * SZ;
  float* kc   = ws + 4 * SZ;
  float* vc   = ws + 5 * SZ;
  float* beta = ws + 6 * SZ;   // 16384 floats
  float* on   = qp;            // scan output / rmsnorm in-place (qp dead then)

  // 1. projections q,k,v
  gemm3_kernel<<<dim3(BT / 64, HK / 64, 3), 256, 0, stream>>>(x, Wq, Wk, Wv, qp, kp, vp);
  // 2. beta
  beta_kernel<<<dim3(BT * Hh / 256), 256, 0, stream>>>(x, Wb, beta);
  // 3. conv + silu + l2norm
  conv_kernel<<<dim3(Bb * Tt * Hh / 4, 1, 3), 256, 0, stream>>>(
      qp, kp, vp, cwq, cwk, cwv, qc, kc, vc);
  // 4. sequential scan: 64 blocks x 4 waves; 4 cols/wave, all-DPP reduce16
  scan_kernel<<<dim3(Bb * Hh * (Vv / 16)), 256, 0, stream>>>(
      qc, kc, vc, beta, on);
  // 5. RMSNorm (in-place)
  rmsnorm_kernel<<<dim3(Bb * Tt * Hh / 4), 256, 0, stream>>>(on, rmsw);
  // 6. output projection
  gemm1_kernel<<<dim3(BT / 64, HK / 64, 1), 256, 0, stream>>>(on, Wo, out);
}